// Round 5
// baseline (371.776 us; speedup 1.0000x reference)
//
#include <hip/hip_runtime.h>
#include <hip/hip_bf16.h>

typedef _Float16 half8  __attribute__((ext_vector_type(8)));
typedef _Float16 half2v __attribute__((ext_vector_type(2)));
typedef float    f32x16 __attribute__((ext_vector_type(16)));

#define KC 32
#define DD 128
#define LL 4
#define NBLK 512      // 2 blocks/CU (64KB LDS each -> 128KB/CU; VGPR occ 2/SIMD)
#define WPB 4
#define NSLOT (NBLK*WPB)

// ---------------------------------------------------------------------------
// helpers
// ---------------------------------------------------------------------------
__device__ inline half2v pkrtz(float a, float b) {
  return __builtin_bit_cast(half2v, __builtin_amdgcn_cvt_pkrtz(a, b));
}
__device__ inline half2v shx2(half2v v, int d) {        // DS-pipe shuffle
  int i = __builtin_bit_cast(int, v);
  i = __shfl_xor(i, d);
  return __builtin_bit_cast(half2v, i);
}
template <int CTRL>
__device__ inline half2v dpp2(half2v v) {
  int i = __builtin_bit_cast(int, v);
  int r = __builtin_amdgcn_update_dpp(i, i, CTRL, 0xF, 0xF, true);
  return __builtin_bit_cast(half2v, r);
}
__device__ inline half2v pmax2(half2v a, half2v b) {
  half2v r;
  r[0] = a[0] > b[0] ? a[0] : b[0];
  r[1] = a[1] > b[1] ? a[1] : b[1];
  return r;
}
__device__ inline half2v sel8(const half2v* p, int i) {
  half2v a = (i & 1) ? p[1] : p[0];
  half2v b = (i & 1) ? p[3] : p[2];
  half2v c = (i & 1) ? p[5] : p[4];
  half2v d = (i & 1) ? p[7] : p[6];
  half2v e = (i & 2) ? b : a;
  half2v f = (i & 2) ? d : c;
  return (i & 4) ? f : e;
}
// async global->LDS, 16B per lane, linear dest (wave base + lane*16)
__device__ inline void stage16(const float* g, float* l) {
  __builtin_amdgcn_global_load_lds(
      (const __attribute__((address_space(1))) void*)g,
      (__attribute__((address_space(3))) void*)l, 16, 0, 0);
}
// raw ds_read_b128 (hidden from the compiler's LDS-DMA alias tracking; our
// manual vmcnt/lgkmcnt discipline carries the ordering)
__device__ inline float4 lds_read16(const float* p) {
  float4 d;
  unsigned a = (unsigned)(unsigned long long)
      (const __attribute__((address_space(3))) float*)p;
  asm volatile("ds_read_b128 %0, %1" : "=v"(d) : "v"(a));
  return d;
}

// ---------------------------------------------------------------------------
// Fused kernel, v5: canonical full-line global accesses.
//  - x staged per-wave via global_load_lds in 4KB slots (32 rows x 32 cols),
//    each 1KB staging instruction covers 16 FULLY-USED 64B lines (the R1-R4
//    pattern touched 32 half-used lines/instr and capped at ~1.7 TB/s
//    independent of schedule/occupancy -> request-tracking bound).
//  - linear LDS dest + XOR-preswizzled GLOBAL source; fragment ds_reads use
//    the matching XOR -> bank-spread.
//  - q/r weight tiles live in 64 VGPRs (frees LDS); z tiles in 32KB LDS.
//  - z-columns remapped (tile zt = latent l, col = component) -> t2 is
//    computed in-lane in f32: no bpermute transport, no quad reduce.
//  - hand-counted vmcnt: per tile, steps wait vmcnt(5,5,4,4); exactly one
//    store per tile (dummy to d_ws when invalid) keeps the ledger exact.
// ---------------------------------------------------------------------------
__global__ __launch_bounds__(256, 2) void mfa_fused(
    const float* __restrict__ x, const float* __restrict__ MU,
    const float* __restrict__ A, const float* __restrict__ D,
    const float* __restrict__ PI, float* __restrict__ out,
    float* __restrict__ dws, int N, int ntiles, int iters)
{
  __shared__ half8 sWz[2048];            // 32 KB z-weights (B-frag order)
  __shared__ float sStage[8192];         // 32 KB: 4 waves x 8KB (2x4KB slots)
  // prologue aliases inside sStage:
  float* sMeta  = sStage + 4096;         // 672 floats: Ri[512]|h[128]|cc[32]
  float* sMetaR = sMeta;
  float* sMetaH = sMeta + 512;
  float* sMetaC = sMeta + 640;

  const int tid = threadIdx.x;
  const int k   = tid >> 3;
  const int sub = tid & 7;
  const int dbase = k*DD + sub*16;

  // ---- phase A: partial Woodbury sums (sPart aliases sStage[0..4096)) ----
  {
    float (*sPart)[8][16] = (float (*)[8][16])sStage;
    float p[16];
#pragma unroll
    for (int i = 0; i < 16; ++i) p[i] = 0.f;
#pragma unroll
    for (int di = 0; di < 16; ++di) {
      const float Dv = D[dbase + di];
      const float id = 1.0f/(Dv*Dv);
      const float mu = MU[dbase + di];
      const float4 a4 = *(const float4*)(A + (size_t)(dbase + di)*LL);
      const float a[LL] = {a4.x, a4.y, a4.z, a4.w};
      int s = 0;
#pragma unroll
      for (int l = 0; l < LL; ++l) {
#pragma unroll
        for (int m2 = 0; m2 <= l; ++m2) { p[s] += a[l]*id*a[m2]; ++s; }
        p[10 + l] += mu*id*a[l];
      }
      p[14] += id*mu*mu;
      p[15] += __logf(Dv*Dv);
    }
#pragma unroll
    for (int i = 0; i < 16; ++i) sPart[k][sub][i] = p[i];
  }
  __syncthreads();

  // ---- phase B: finalize per-component factorization ----
  if (tid < KC) {
    float (*sPart)[8][16] = (float (*)[8][16])sStage;
    const int kk = tid;
    float p[16];
#pragma unroll
    for (int i = 0; i < 16; ++i) p[i] = 0.f;
    for (int s = 0; s < 8; ++s)
#pragma unroll
      for (int i = 0; i < 16; ++i) p[i] += sPart[kk][s][i];

    float Lm[LL][LL];
    {
      int s = 0;
      for (int l = 0; l < LL; ++l)
        for (int m2 = 0; m2 <= l; ++m2) { Lm[l][m2] = p[s]; ++s; }
    }
    for (int l = 0; l < LL; ++l) Lm[l][l] += 1.0f;
    float cv[LL];
    for (int l = 0; l < LL; ++l) cv[l] = p[10 + l];
    const float t_const  = p[14];
    const float sumlogD2 = p[15];

    float Lo[LL][LL];
    for (int i = 0; i < LL; ++i)
      for (int j = 0; j < LL; ++j) Lo[i][j] = 0.f;
    for (int i = 0; i < LL; ++i) {
      float s = Lm[i][i];
      for (int m2 = 0; m2 < i; ++m2) s -= Lo[i][m2]*Lo[i][m2];
      Lo[i][i] = sqrtf(s);
      for (int j = i + 1; j < LL; ++j) {
        float t = Lm[j][i];
        for (int m2 = 0; m2 < i; ++m2) t -= Lo[j][m2]*Lo[i][m2];
        Lo[j][i] = t / Lo[i][i];
      }
    }
    float Ri[LL][LL];
    for (int i = 0; i < LL; ++i)
      for (int j = 0; j < LL; ++j) Ri[i][j] = 0.f;
    for (int i = 0; i < LL; ++i) {
      Ri[i][i] = 1.0f/Lo[i][i];
      for (int j = 0; j < i; ++j) {
        float s = 0.f;
        for (int m2 = j; m2 < i; ++m2) s += Lo[i][m2]*Ri[m2][j];
        Ri[i][j] = -s / Lo[i][i];
      }
    }
    for (int i = 0; i < LL; ++i)
      for (int j = 0; j < LL; ++j) sMetaR[kk*16 + i*4 + j] = Ri[i][j];
    for (int l = 0; l < LL; ++l) {
      float s = 0.f;
      for (int m2 = 0; m2 <= l; ++m2) s += Ri[l][m2]*cv[m2];
      sMetaH[kk*LL + l] = s;
    }
    float logdetL = 0.f;
    for (int i = 0; i < LL; ++i) logdetL += __logf(Lo[i][i]);
    logdetL *= 2.0f;
    const float dlog2pi = 235.24826473f;  // 128*log(2*pi)
    sMetaC[kk] = PI[kk] - 0.5f*(dlog2pi + logdetL + sumlogD2) - 0.5f*t_const;
  }
  __syncthreads();

  // ---- phase C: z-weights -> LDS (tile zt = latent l, col = component) ----
  {
    float Rm[LL][LL];
#pragma unroll
    for (int l = 0; l < LL; ++l)
#pragma unroll
      for (int m = 0; m < LL; ++m) Rm[l][m] = sMetaR[k*16 + l*4 + m];
    const float sc = 0.70710678118654752f;
#pragma unroll
    for (int h2 = 0; h2 < 2; ++h2) {
      half8 vz0, vz1, vz2, vz3;
#pragma unroll
      for (int j = 0; j < 8; ++j) {
        const int di = 8*h2 + j;
        const float Dv = D[dbase + di];
        const float id = 1.0f/(Dv*Dv);
        const float4 a4 = *(const float4*)(A + (size_t)(dbase + di)*LL);
        const float s0 = a4.x*Rm[0][0];
        const float s1 = a4.x*Rm[1][0] + a4.y*Rm[1][1];
        const float s2 = a4.x*Rm[2][0] + a4.y*Rm[2][1] + a4.z*Rm[2][2];
        const float s3 = a4.x*Rm[3][0] + a4.y*Rm[3][1] + a4.z*Rm[3][2]
                       + a4.w*Rm[3][3];
        vz0[j] = (_Float16)(sc*id*s0);
        vz1[j] = (_Float16)(sc*id*s1);
        vz2[j] = (_Float16)(sc*id*s2);
        vz3[j] = (_Float16)(sc*id*s3);
      }
      const int lp = (h2 << 5) | k;
      sWz[(0*8 + sub)*64 + lp] = vz0;
      sWz[(1*8 + sub)*64 + lp] = vz1;
      sWz[(2*8 + sub)*64 + lp] = vz2;
      sWz[(3*8 + sub)*64 + lp] = vz3;
    }
  }

  // ---- per-lane constants + q/r weight fragments in registers ----
  const int wv = tid >> 6, lane = tid & 63;
  const int c = lane & 31;                 // component / output col
  const int h = lane >> 5;                 // k-half
  const int sw7 = c & 7;
  const float cc = sMetaC[c];
  float hz[4];
#pragma unroll
  for (int zt = 0; zt < 4; ++zt)
    hz[zt] = 0.70710678118654752f * sMetaH[c*4 + zt];

  half8 qf[8], rf[8];
#pragma unroll
  for (int ss = 0; ss < 8; ++ss) {
    const float* dp = D  + (size_t)c*DD + ss*16 + h*8;
    const float* mp = MU + (size_t)c*DD + ss*16 + h*8;
    const float4 d0 = *(const float4*)dp, d1 = *(const float4*)(dp + 4);
    const float4 m0 = *(const float4*)mp, m1 = *(const float4*)(mp + 4);
    const float i0 = 1.f/(d0.x*d0.x), i1 = 1.f/(d0.y*d0.y);
    const float i2 = 1.f/(d0.z*d0.z), i3 = 1.f/(d0.w*d0.w);
    const float i4 = 1.f/(d1.x*d1.x), i5 = 1.f/(d1.y*d1.y);
    const float i6 = 1.f/(d1.z*d1.z), i7 = 1.f/(d1.w*d1.w);
    union { half8 v; half2v p[4]; } q, r;
    q.p[0] = pkrtz(-0.5f*i0, -0.5f*i1);
    q.p[1] = pkrtz(-0.5f*i2, -0.5f*i3);
    q.p[2] = pkrtz(-0.5f*i4, -0.5f*i5);
    q.p[3] = pkrtz(-0.5f*i6, -0.5f*i7);
    r.p[0] = pkrtz(i0*m0.x, i1*m0.y);
    r.p[1] = pkrtz(i2*m0.z, i3*m0.w);
    r.p[2] = pkrtz(i4*m1.x, i5*m1.y);
    r.p[3] = pkrtz(i6*m1.z, i7*m1.w);
    qf[ss] = q.v; rf[ss] = r.v;
  }
  __syncthreads();   // sWz visible; sMeta consumed; sStage free for staging

  const int tbase = (int)blockIdx.x*WPB + wv;
  const int gid   = (int)blockIdx.x*256 + tid;

  // stage slot (itS, slS): 32 rows x 32 cols f32, linear LDS dest,
  // XOR-preswizzled global src (16B chunk p holds logical chunk p^(row&7)).
  auto stageF = [&](int itS, int slS) {
    const int trow = (itS*NSLOT + tbase)*32;
    float* lb = sStage + wv*2048 + (slS & 1)*1024;
#pragma unroll
    for (int m = 0; m < 4; ++m) {
      int r0 = trow + m*8 + (lane >> 3);
      if (r0 >= N) r0 = N - 1;
      const float* src = x + (size_t)r0*DD + slS*32
                       + 4*((lane & 7) ^ ((lane >> 3) & 7));
      stage16(src, lb + m*256);
    }
  };

#define MM(SS, XA, XB)                                                        \
  {                                                                           \
    union { half8 v; half2v p[4]; } hx, hx2;                                  \
    hx.p[0] = pkrtz((XA).x, (XA).y);                                          \
    hx.p[1] = pkrtz((XA).z, (XA).w);                                          \
    hx.p[2] = pkrtz((XB).x, (XB).y);                                          \
    hx.p[3] = pkrtz((XB).z, (XB).w);                                          \
    hx2.v = hx.v * hx.v;                                                      \
    acc[0] = __builtin_amdgcn_mfma_f32_32x32x16_f16(hx2.v, qf[SS], acc[0], 0,0,0); \
    acc[1] = __builtin_amdgcn_mfma_f32_32x32x16_f16(hx.v, sWz[(0*8+(SS))*64 + lane], acc[1], 0,0,0); \
    acc[2] = __builtin_amdgcn_mfma_f32_32x32x16_f16(hx.v, sWz[(1*8+(SS))*64 + lane], acc[2], 0,0,0); \
    acc[3] = __builtin_amdgcn_mfma_f32_32x32x16_f16(hx.v, sWz[(2*8+(SS))*64 + lane], acc[3], 0,0,0); \
    acc[4] = __builtin_amdgcn_mfma_f32_32x32x16_f16(hx.v, sWz[(3*8+(SS))*64 + lane], acc[4], 0,0,0); \
    acc[0] = __builtin_amdgcn_mfma_f32_32x32x16_f16(hx.v, rf[SS], acc[0], 0,0,0); \
  }

  // one K-step over a staged 32-col slot SL; waits vmcnt(WVM); then stages
  // the slot 2 ahead (same physical buffer, reads already complete).
#define STEPK(SL, WVMSTR, ITS, SLS)                                           \
  {                                                                           \
    asm volatile("s_waitcnt vmcnt(" WVMSTR ")" ::: "memory");                 \
    __builtin_amdgcn_sched_barrier(0);                                        \
    const float* sb = sStage + wv*2048 + ((SL) & 1)*1024 + (size_t)c*32;      \
    const float4 xa0 = lds_read16(sb + (((2*h + 0) ^ sw7) << 2));             \
    const float4 xa1 = lds_read16(sb + (((2*h + 1) ^ sw7) << 2));             \
    const float4 xb0 = lds_read16(sb + (((4 + 2*h + 0) ^ sw7) << 2));         \
    const float4 xb1 = lds_read16(sb + (((4 + 2*h + 1) ^ sw7) << 2));         \
    asm volatile("s_waitcnt lgkmcnt(0)" ::: "memory");                        \
    __builtin_amdgcn_sched_barrier(0);                                        \
    stageF((ITS), (SLS));                                                     \
    __builtin_amdgcn_sched_barrier(0);                                        \
    MM((SL)*2 + 0, xa0, xa1);                                                 \
    MM((SL)*2 + 1, xb0, xb1);                                                 \
  }

  // prologue: 2 slots in flight + 1 dummy store (fixed vmcnt ledger shape)
  stageF(0, 0);
  stageF(0, 1);
  dws[gid] = 0.f;
  __builtin_amdgcn_sched_barrier(0);

  for (int it = 0; it < iters; ++it) {
    f32x16 acc[5];
#pragma unroll
    for (int t = 0; t < 5; ++t)
#pragma unroll
      for (int r = 0; r < 16; ++r) acc[t][r] = 0.f;

    STEPK(0, "5", it,     2)
    STEPK(1, "5", it,     3)
    STEPK(2, "4", it + 1, 0)
    STEPK(3, "4", it + 1, 1)

    // ---- epilogue: all in-lane (col c = component), then lsexp ladders ----
    float vp[16];
#pragma unroll
    for (int r = 0; r < 16; ++r) vp[r] = acc[0][r] + cc;
#pragma unroll
    for (int zt = 0; zt < 4; ++zt)
#pragma unroll
      for (int r = 0; r < 16; ++r) {
        const float e = acc[1 + zt][r] - hz[zt];
        vp[r] += e*e;
      }

    half2v pm[8];
#pragma unroll
    for (int i = 0; i < 8; ++i) pm[i] = pkrtz(vp[2*i], vp[2*i + 1]);
#pragma unroll
    for (int i = 0; i < 8; ++i) {
      pm[i] = pmax2(pm[i], dpp2<0xB1>(pm[i]));
      pm[i] = pmax2(pm[i], dpp2<0x4E>(pm[i]));
      pm[i] = pmax2(pm[i], dpp2<0x141>(pm[i]));
      pm[i] = pmax2(pm[i], dpp2<0x140>(pm[i]));
      pm[i] = pmax2(pm[i], shx2(pm[i], 16));
    }
    half2v ps[8];
#pragma unroll
    for (int i = 0; i < 8; ++i) {
      const float e0 = __expf(vp[2*i]     - (float)pm[i][0]);
      const float e1 = __expf(vp[2*i + 1] - (float)pm[i][1]);
      ps[i] = pkrtz(e0, e1);
    }
#pragma unroll
    for (int i = 0; i < 8; ++i) {
      ps[i] = ps[i] + dpp2<0xB1>(ps[i]);
      ps[i] = ps[i] + dpp2<0x4E>(ps[i]);
      ps[i] = ps[i] + dpp2<0x141>(ps[i]);
      ps[i] = ps[i] + dpp2<0x140>(ps[i]);
      ps[i] = ps[i] + shx2(ps[i], 16);
    }

    // exactly ONE store per tile (all lanes; invalid lanes -> dws dummy)
    const int tile = it*NSLOT + tbase;
    const half2v S = sel8(ps, (c & 15) >> 1);
    const half2v M = sel8(pm, (c & 15) >> 1);
    const float sum = (c & 1) ? (float)S[1] : (float)S[0];
    const float mx  = (c & 1) ? (float)M[1] : (float)M[0];
    const int rw = tile*32 + (c & 3) + 8*((c & 15) >> 2) + 4*h;
    const bool valid = (tile < ntiles) && (c < 16) && (rw < N);
    float* dst = valid ? (out + rw) : (dws + gid);
    *dst = mx + __logf(sum);
  }
#undef STEPK
#undef MM
}

extern "C" void kernel_launch(void* const* d_in, const int* in_sizes, int n_in,
                              void* d_out, int out_size, void* d_ws, size_t ws_size,
                              hipStream_t stream) {
  (void)n_in; (void)out_size; (void)ws_size;
  const float* x  = (const float*)d_in[0];
  const float* MU = (const float*)d_in[1];
  const float* A  = (const float*)d_in[2];
  const float* D  = (const float*)d_in[3];
  const float* PI = (const float*)d_in[4];
  float* out = (float*)d_out;
  float* dws = (float*)d_ws;

  const int N = in_sizes[0] / DD;
  const int ntiles = (N + 31) / 32;
  const int iters  = (ntiles + NSLOT - 1) / NSLOT;
  hipLaunchKernelGGL(mfa_fused, dim3(NBLK), dim3(256), 0, stream,
                     x, MU, A, D, PI, out, dws, N, ntiles, iters);
}